// Round 5
// baseline (1010.448 us; speedup 1.0000x reference)
//
#include <hip/hip_runtime.h>
#include <hip/hip_bf16.h>
#include <math.h>

typedef __hip_bfloat16 bf16;
typedef __attribute__((ext_vector_type(8))) short short8;
typedef __attribute__((ext_vector_type(4))) float f32x4;

#define BB 4096
#define LL 8
#define NN 9
#define SS 877
#define DD 256
#define D2 512
#define TT 137
#define HH 128
#define MM (BB*NN)   // 36864
#define KP1 896      // 877 padded to mult of 32

__device__ __forceinline__ float lrelu(float x){ return x > 0.f ? x : 0.01f*x; }
__device__ __forceinline__ float gelu_tanh(float x){
    float x3 = x*x*x;
    float t = tanhf(0.7978845608028654f*(x + 0.044715f*x3));
    return 0.5f*x*(1.f + t);
}
__device__ __forceinline__ short f2b(float x){
    union { bf16 h; short s; } u; u.h = __float2bfloat16(x); return u.s;
}
__device__ __forceinline__ float b2f(bf16 v){ return __bfloat162float(v); }

// async global->LDS, 16B per lane; ldst is wave-uniform base, HW adds lane*16
__device__ __forceinline__ void glds16(const void* gsrc, void* ldst){
    __builtin_amdgcn_global_load_lds(
        (const __attribute__((address_space(1))) void*)gsrc,
        (__attribute__((address_space(3))) void*)ldst,
        16, 0, 0);
}

// ---------- fused swizzle of ALL weights into fragment order -------------------
// dst flat = (((kb*NBt + nbOff+nbl)*8 + h)*64 + lane)*8 + j
//   k = kb*32 + (lane>>4)*8 + j ; n_local = nbl*128 + h*16 + (lane&15)
struct SwzD { const float* src; unsigned short* dst; int K; int Nloc; int NBloc;
              int NBt; int nbOff; long long base; };
struct SwzTab { SwzD d[10]; long long total; };

__global__ __launch_bounds__(256) void k_swzall(SwzTab tab){
    for (long long f0 = (long long)blockIdx.x*256 + threadIdx.x; f0 < tab.total;
         f0 += (long long)gridDim.x*256){
        int di = 0;
        #pragma unroll
        for (int q = 1; q < 10; q++) if (f0 >= tab.d[q].base) di = q;
        const SwzD dd = tab.d[di];
        long long f = f0 - dd.base;
        int j = (int)(f & 7); int lane = (int)((f>>3)&63); int h = (int)((f>>9)&7);
        long long u = f>>12;
        int nbl = (int)(u % dd.NBloc), kb = (int)(u / dd.NBloc);
        int k = kb*32 + ((lane>>4)<<3) + j;
        int n = nbl*128 + h*16 + (lane&15);
        float v = (k < dd.K) ? dd.src[(size_t)k*dd.Nloc + n] : 0.f;
        size_t dsti = ((((size_t)kb*dd.NBt + dd.nbOff + nbl)*8 + h)*64 + lane)*8 + j;
        dd.dst[dsti] = (unsigned short)f2b(v);
    }
}

// ---------- prep: valid mask + x -> bf16 [MM][896] (zero-padded) ---------------
__global__ __launch_bounds__(256) void k_prep(const float* __restrict__ src,
                                              const float* __restrict__ srcn,
                                              float* __restrict__ vm,
                                              unsigned short* __restrict__ xbf){
    int m = blockIdx.x; int b = m / NN, n = m % NN;
    const float* row = (n == 0) ? src + (size_t)b*SS
                                : srcn + ((size_t)b*LL + (n-1))*SS;
    unsigned short* orow = xbf + (size_t)m*KP1;
    float s = 0.f;
    for (int i = threadIdx.x; i < KP1; i += 256){
        float v = (i < SS) ? row[i] : 0.f;
        s += fabsf(v);
        orow[i] = (unsigned short)f2b(v);
    }
    #pragma unroll
    for (int o = 32; o > 0; o >>= 1) s += __shfl_xor(s, o);
    __shared__ float part[4];
    if ((threadIdx.x & 63) == 0) part[threadIdx.x>>6] = s;
    __syncthreads();
    if (threadIdx.x == 0)
        vm[m] = ((part[0]+part[1]+part[2]+part[3]) > 0.f) ? 1.f : 0.f;
}

// ---------- epilogue modes ------------------------------------------------------
#define EPI_NONE 0
#define EPI_BN_LEAKY 1
#define EPI_RES 2
#define EPI_GELU 3
#define EPI_ENC2 4   // bn_leaky + (role + class)*vm, dual store

// ---------- MFMA GEMM, m97-style: dbuf LDS for A and W via global_load_lds -----
__global__ __launch_bounds__(256) void k_mgemm(
    const unsigned short* __restrict__ A, int lda,
    const unsigned short* __restrict__ Wsw, int NBt, int nKb,
    const float* __restrict__ bias, const float* __restrict__ bng,
    const float* __restrict__ bnb, const float* __restrict__ res,
    int res_stride, int mode,
    float* __restrict__ out, bf16* __restrict__ outbf, int ldo,
    const float* __restrict__ ci, const float* __restrict__ ctok,
    const float* __restrict__ tokc, const float* __restrict__ tokn1,
    const float* __restrict__ tokn2, const float* __restrict__ vmp)
{
    __shared__ short8 As[2][8][64];     // [buf][row-grp][lane]  16KB
    __shared__ short8 Ws[2][8][64];     // [buf][h-frag][lane]   16KB
    __shared__ float ciS[128][13];
    __shared__ float vmS[128];
    int row0 = blockIdx.x*128;
    int nb = blockIdx.y;
    int tid = threadIdx.x;
    int wv = tid>>6, lane = tid&63;
    int wr = wv>>1, wc = wv&1, quad = lane>>4, l15 = lane&15;

    if (mode == EPI_ENC2){
        for (int l = tid; l < 128*13; l += 256){
            int r = l/13, c = l - r*13;
            ciS[r][c] = ci[(size_t)(row0+r)*13 + c];
        }
        for (int l = tid; l < 128; l += 256) vmS[l] = vmp[row0+l];
    }

    f32x4 zz = {0.f,0.f,0.f,0.f};
    f32x4 acc[4][4];
    #pragma unroll
    for (int i=0;i<4;i++){ acc[i][0]=zz; acc[i][1]=zz; acc[i][2]=zz; acc[i][3]=zz; }

    // stage kb into LDS buffer buf (4 glds per wave)
    #define STAGE(kb_, buf_) do{                                                   \
        int kb__ = (kb_);                                                          \
        for (int e = 0; e < 2; e++){                                               \
            int grp = wv + e*4;                                                    \
            const unsigned short* g = A + (size_t)(row0 + grp*16 + l15)*lda        \
                                        + kb__*32 + quad*8;                        \
            glds16(g, &As[buf_][grp][0]);                                          \
        }                                                                          \
        for (int e = 0; e < 2; e++){                                               \
            int h = wv*2 + e;                                                      \
            const unsigned short* g = Wsw +                                        \
                ((((size_t)kb__*NBt + nb)*8 + h)*64 + lane)*8;                     \
            glds16(g, &Ws[buf_][h][0]);                                            \
        }                                                                          \
    }while(0)

    STAGE(0, 0);
    for (int kb = 0; kb < nKb; kb++){
        int buf = kb & 1;
        __syncthreads();                       // drains glds for buf
        if (kb+1 < nKb) STAGE(kb+1, buf^1);    // overlaps with MFMAs below
        short8 afr[4], bfr[4];
        #pragma unroll
        for (int i = 0; i < 4; i++) afr[i] = As[buf][wr*4+i][lane];
        #pragma unroll
        for (int h = 0; h < 4; h++) bfr[h] = Ws[buf][wc*4+h][lane];
        #pragma unroll
        for (int i = 0; i < 4; i++)
            #pragma unroll
            for (int h = 0; h < 4; h++)
                acc[i][h] = __builtin_amdgcn_mfma_f32_16x16x32_bf16(afr[i], bfr[h], acc[i][h], 0,0,0);
    }
    #undef STAGE

    const float inv = rsqrtf(1.f + 1e-5f);
    #pragma unroll
    for (int i = 0; i < 4; i++){
        int rl0 = wr*64 + i*16 + quad*4;
        #pragma unroll
        for (int h = 0; h < 4; h++){
            int c = nb*128 + wc*64 + h*16 + l15;
            float bi = bias ? bias[c] : 0.f;
            #pragma unroll
            for (int reg = 0; reg < 4; reg++){
                int rl = rl0 + reg;
                int r = row0 + rl;
                float y = acc[i][h][reg] + bi;
                if (mode == EPI_BN_LEAKY){
                    y = lrelu(y*(bng[c]*inv) + bnb[c]);
                } else if (mode == EPI_ENC2){
                    y = lrelu(y*(bng[c]*inv) + bnb[c]);
                    int n = r % NN;
                    float role = (n==0) ? tokc[c] : ((n<=4) ? tokn1[c] : tokn2[c]);
                    float cl = 0.f;
                    #pragma unroll
                    for (int tck = 0; tck < 13; tck++)
                        cl += ciS[rl][tck] * ctok[tck*DD + c];
                    y += (role + cl) * vmS[rl];
                } else if (mode == EPI_RES){
                    y += res[(size_t)r*res_stride + c];
                } else if (mode == EPI_GELU){
                    y = gelu_tanh(y);
                }
                if (out)   out[(size_t)r*ldo + c] = y;
                if (outbf) outbf[(size_t)r*ldo + c] = __float2bfloat16(y);
            }
        }
    }
}

// ---------- pred head v2: feat resident in regs, barrier-free t-loop -----------
__global__ __launch_bounds__(256) void k_pred2(
    const unsigned short* __restrict__ feat,   // bf16 [4096][256]
    const unsigned short* __restrict__ Wsw,    // frag-ordered [t*8+kb][h][lane][j]
    const float* __restrict__ b1, const float* __restrict__ bg,
    const float* __restrict__ bb, const float* __restrict__ w2,
    float* __restrict__ outp)
{
    __shared__ short8 Af[8][8][64];            // [kb][grp][lane] 64KB
    int row0 = blockIdx.x*128;
    int t0 = blockIdx.y*8;
    int tid = threadIdx.x;
    int wv = tid>>6, lane = tid&63;
    int quad = lane>>4, l15 = lane&15;

    #pragma unroll
    for (int kb = 0; kb < 8; kb++){
        #pragma unroll
        for (int e = 0; e < 2; e++){
            int grp = wv*2 + e;
            const unsigned short* g = feat + (size_t)(row0 + grp*16 + l15)*DD
                                           + kb*32 + quad*8;
            glds16(g, &Af[kb][grp][0]);
        }
    }
    __syncthreads();
    short8 areg[2][8];
    #pragma unroll
    for (int i = 0; i < 2; i++)
        #pragma unroll
        for (int kb = 0; kb < 8; kb++)
            areg[i][kb] = Af[kb][wv*2+i][lane];

    const short8* W8 = (const short8*)Wsw;
    const float inv = rsqrtf(1.f + 1e-5f);
    f32x4 zz = {0.f,0.f,0.f,0.f};

    for (int tt = 0; tt < 8; tt++){
        int t = t0 + tt;
        if (t >= TT) break;
        f32x4 acc[2][8];
        #pragma unroll
        for (int i=0;i<2;i++)
            #pragma unroll
            for (int h=0;h<8;h++) acc[i][h] = zz;
        #pragma unroll
        for (int kb = 0; kb < 8; kb++){
            short8 w[8];
            #pragma unroll
            for (int h = 0; h < 8; h++)
                w[h] = W8[((size_t)(t*8 + kb)*8 + h)*64 + lane];
            #pragma unroll
            for (int i = 0; i < 2; i++)
                #pragma unroll
                for (int h = 0; h < 8; h++)
                    acc[i][h] = __builtin_amdgcn_mfma_f32_16x16x32_bf16(areg[i][kb], w[h], acc[i][h], 0,0,0);
        }
        float b1v[8], bgv[8], bbv[8], w2v[8];
        #pragma unroll
        for (int h = 0; h < 8; h++){
            int hc = t*HH + h*16 + l15;
            b1v[h] = b1[hc]; bgv[h] = bg[hc]*inv; bbv[h] = bb[hc]; w2v[h] = w2[hc];
        }
        #pragma unroll
        for (int i = 0; i < 2; i++){
            #pragma unroll
            for (int reg = 0; reg < 4; reg++){
                float p = 0.f;
                #pragma unroll
                for (int h = 0; h < 8; h++){
                    float y = (acc[i][h][reg] + b1v[h])*bgv[h] + bbv[h];
                    p += lrelu(y) * w2v[h];
                }
                p += __shfl_xor(p, 1);
                p += __shfl_xor(p, 2);
                p += __shfl_xor(p, 4);
                p += __shfl_xor(p, 8);
                if (l15 == 0){
                    int r = row0 + wv*32 + i*16 + quad*4 + reg;
                    outp[(size_t)r*TT + t] = p;
                }
            }
        }
    }
}

// ---------- LN helpers (wave shfl + 2 barriers) --------------------------------
__device__ __forceinline__ float blksum(float v, float* part){
    #pragma unroll
    for (int o = 32; o > 0; o >>= 1) v += __shfl_xor(v, o);
    __syncthreads();
    if ((threadIdx.x & 63) == 0) part[threadIdx.x>>6] = v;
    __syncthreads();
    return part[0]+part[1]+part[2]+part[3];
}

__global__ __launch_bounds__(256) void k_lnchain(const float* __restrict__ in,
                                                 const float* __restrict__ g1, const float* __restrict__ b1,
                                                 const float* __restrict__ g2, const float* __restrict__ b2,
                                                 float* __restrict__ fo1, bf16* __restrict__ hn){
    __shared__ float part[4];
    int m = blockIdx.x, d = threadIdx.x;
    float x = in[(size_t)m*DD + d];
    float mu = blksum(x, part) * (1.f/256.f);
    float dx = x - mu;
    float var = blksum(dx*dx, part) * (1.f/256.f);
    float y = dx * rsqrtf(var + 1e-5f) * g1[d] + b1[d];
    y = fmaxf(y, 0.f);
    fo1[(size_t)m*DD + d] = y;
    float mu2 = blksum(y, part) * (1.f/256.f);
    float dy = y - mu2;
    float var2 = blksum(dy*dy, part) * (1.f/256.f);
    hn[(size_t)m*DD + d] = __float2bfloat16(dy * rsqrtf(var2 + 1e-5f) * g2[d] + b2[d]);
}

__global__ __launch_bounds__(256) void k_ln(const float* __restrict__ in,
                                            const float* __restrict__ g, const float* __restrict__ b,
                                            bf16* __restrict__ out){
    __shared__ float part[4];
    int m = blockIdx.x, d = threadIdx.x;
    float x = in[(size_t)m*DD + d];
    float mu = blksum(x, part) * (1.f/256.f);
    float dx = x - mu;
    float var = blksum(dx*dx, part) * (1.f/256.f);
    out[(size_t)m*DD + d] = __float2bfloat16(dx * rsqrtf(var + 1e-5f) * g[d] + b[d]);
}

// ---------- attention (query token 0 only), combined kv [MM][512] --------------
__global__ __launch_bounds__(256) void k_attn(const bf16* __restrict__ q,
                                              const bf16* __restrict__ kv,
                                              const float* __restrict__ vm,
                                              bf16* __restrict__ o){
    int b = blockIdx.x, t = threadIdx.x;
    __shared__ float ks[NN][DD];
    __shared__ float vs[NN][DD];
    __shared__ float qs[DD];
    __shared__ float sc[4][NN];
    __shared__ float val[NN];
    qs[t] = b2f(q[(size_t)b*DD + t]);
    for (int j = 0; j < NN; j++){
        ks[j][t] = b2f(kv[((size_t)b*NN + j)*D2 + t]);
        vs[j][t] = b2f(kv[((size_t)b*NN + j)*D2 + DD + t]);
    }
    if (t < NN) val[t] = vm[b*NN + t];
    __syncthreads();
    if (t < 4*NN){
        int h = t / NN, j = t % NN;
        float s = 0.f;
        for (int d = 0; d < 64; d++) s += qs[h*64+d] * ks[j][h*64+d];
        s *= 0.125f;
        if (!(val[j] > 0.f)) s = -1e9f;
        sc[h][j] = s;
    }
    __syncthreads();
    if (t < 4){
        float mx = -1e30f;
        for (int j = 0; j < NN; j++) mx = fmaxf(mx, sc[t][j]);
        float den = 0.f;
        for (int j = 0; j < NN; j++){ float e = expf(sc[t][j]-mx); sc[t][j] = e; den += e; }
        float iv = 1.f/den;
        for (int j = 0; j < NN; j++) sc[t][j] *= iv;
    }
    __syncthreads();
    int h = t >> 6;
    float acc = 0.f;
    for (int j = 0; j < NN; j++) acc += sc[h][j] * vs[j][t];
    o[(size_t)b*DD + t] = __float2bfloat16(acc);
}

extern "C" void kernel_launch(void* const* d_in, const int* in_sizes, int n_in,
                              void* d_out, int out_size, void* d_ws, size_t ws_size,
                              hipStream_t stream) {
    const float* src      = (const float*)d_in[0];
    const float* srcn     = (const float*)d_in[1];
    const float* cell_inf = (const float*)d_in[2];
    const float* enc_w1   = (const float*)d_in[3];
    const float* enc_b1   = (const float*)d_in[4];
    const float* bn1g     = (const float*)d_in[5];
    const float* bn1b     = (const float*)d_in[6];
    const float* enc_w2   = (const float*)d_in[7];
    const float* enc_b2   = (const float*)d_in[8];
    const float* bn2g     = (const float*)d_in[9];
    const float* bn2b     = (const float*)d_in[10];
    const float* proj_w   = (const float*)d_in[11];
    const float* proj_b   = (const float*)d_in[12];
    const float* pln_g    = (const float*)d_in[13];
    const float* pln_b    = (const float*)d_in[14];
    const float* aln_g    = (const float*)d_in[15];
    const float* aln_b    = (const float*)d_in[16];
    const float* wq       = (const float*)d_in[17];
    const float* wk       = (const float*)d_in[18];
    const float* wv       = (const float*)d_in[19];
    const float* wo       = (const float*)d_in[20];
    const float* wo_b     = (const float*)d_in[21];
    const float* fln_g    = (const float*)d_in[22];
    const float* fln_b    = (const float*)d_in[23];
    const float* ff_w1    = (const float*)d_in[24];
    const float* ff_b1    = (const float*)d_in[25];
    const float* ff_w2    = (const float*)d_in[26];
    const float* ff_b2    = (const float*)d_in[27];
    const float* tokc     = (const float*)d_in[28];
    const float* tokn1    = (const float*)d_in[29];
    const float* tokn2    = (const float*)d_in[30];
    const float* cell_tok = (const float*)d_in[31];
    const float* pw1      = (const float*)d_in[32];
    const float* pb1      = (const float*)d_in[33];
    const float* pbg      = (const float*)d_in[34];
    const float* pbb      = (const float*)d_in[35];
    const float* pw2      = (const float*)d_in[36];
    float* out            = (float*)d_out;

    char* base = (char*)d_ws;
    size_t off = 0;
    auto alloc = [&](size_t bytes)->char*{
        char* p = base + off;
        off += (bytes + 255) & ~(size_t)255;
        return p;
    };
    // swizzled weights (bf16)
    bf16* sw_enc1 = (bf16*)alloc((size_t)KP1*D2*2);
    bf16* sw_enc2 = (bf16*)alloc((size_t)D2*DD*2);
    bf16* sw_proj = (bf16*)alloc((size_t)DD*DD*2);
    bf16* sw_wq   = (bf16*)alloc((size_t)DD*DD*2);
    bf16* sw_kv   = (bf16*)alloc((size_t)DD*D2*2);     // wk|wv combined, NBt=4
    bf16* sw_wo   = (bf16*)alloc((size_t)DD*DD*2);
    bf16* sw_ff1  = (bf16*)alloc((size_t)DD*D2*2);
    bf16* sw_ff2  = (bf16*)alloc((size_t)D2*DD*2);
    bf16* sw_pred = (bf16*)alloc((size_t)TT*DD*HH*2);
    // activations (with aliasing)
    float* vm    = (float*)alloc((size_t)MM*4);
    char*  xreg  = alloc((size_t)MM*KP1*2);           // xbf; later fo + fobf
    bf16*  h1bf  = (bf16*)alloc((size_t)MM*D2*2);     // later: kv combined [MM][512]
    float* t0    = (float*)alloc((size_t)MM*DD*4);
    bf16*  hnbf  = (bf16*)alloc((size_t)MM*DD*2);
    bf16*  qbf   = (bf16*)alloc((size_t)BB*DD*2);
    bf16*  obbf  = (bf16*)alloc((size_t)BB*DD*2);
    float* fo2   = (float*)alloc((size_t)BB*DD*4);
    bf16*  hn2bf = (bf16*)alloc((size_t)BB*DD*2);
    bf16*  g1bf  = (bf16*)alloc((size_t)BB*D2*2);
    bf16*  featbf= (bf16*)alloc((size_t)BB*DD*2);
    // aliases
    unsigned short* xbf = (unsigned short*)xreg;                  // dead after enc1
    float* fo   = (float*)xreg;                                   // MM*DD fp32
    bf16*  fobf = (bf16*)(xreg + (size_t)MM*DD*4);                // MM*DD bf16
    bf16* kvbf  = h1bf;                                           // after enc2

    dim3 blk(256);

    // fused weight swizzle
    SwzTab tab;
    long long cum = 0;
    auto mk = [&](int slot, const float* s, bf16* d, int K, int Kpad, int Nloc,
                  int NBt, int nbOff){
        tab.d[slot] = SwzD{ s, (unsigned short*)d, K, Nloc, Nloc/128, NBt, nbOff, cum };
        cum += (long long)Kpad*Nloc;
    };
    mk(0, enc_w1, sw_enc1, SS, KP1, D2, 4, 0);
    mk(1, enc_w2, sw_enc2, D2, D2, DD, 2, 0);
    mk(2, proj_w, sw_proj, DD, DD, DD, 2, 0);
    mk(3, wq,     sw_wq,   DD, DD, DD, 2, 0);
    mk(4, wk,     sw_kv,   DD, DD, DD, 4, 0);
    mk(5, wv,     sw_kv,   DD, DD, DD, 4, 2);
    mk(6, wo,     sw_wo,   DD, DD, DD, 2, 0);
    mk(7, ff_w1,  sw_ff1,  DD, DD, D2, 4, 0);
    mk(8, ff_w2,  sw_ff2,  D2, D2, DD, 2, 0);
    mk(9, pw1,    sw_pred, TT*DD, TT*DD, HH, 1, 0);
    tab.total = cum;
    k_swzall<<<1024, blk, 0, stream>>>(tab);

    // prep: vm + bf16 x
    k_prep<<<MM, blk, 0, stream>>>(src, srcn, vm, xbf);

    // enc1: (M,896)@(896,512) -> bn1 -> leaky -> h1bf (bf16)
    k_mgemm<<<dim3(MM/128, 4), blk, 0, stream>>>(xbf, KP1,
        (const unsigned short*)sw_enc1, 4, KP1/32, enc_b1, bn1g, bn1b,
        nullptr, 0, EPI_BN_LEAKY, nullptr, h1bf, D2,
        nullptr, nullptr, nullptr, nullptr, nullptr, nullptr);
    // enc2 + role/class fused: -> fo (fp32) + fobf (bf16)   [xbf now dead]
    k_mgemm<<<dim3(MM/128, 2), blk, 0, stream>>>((const unsigned short*)h1bf, D2,
        (const unsigned short*)sw_enc2, 2, 16, enc_b2, bn2g, bn2b,
        nullptr, 0, EPI_ENC2, fo, fobf, DD,
        cell_inf, cell_tok, tokc, tokn1, tokn2, vm);
    // proj -> t0 (fp32)
    k_mgemm<<<dim3(MM/128, 2), blk, 0, stream>>>((const unsigned short*)fobf, DD,
        (const unsigned short*)sw_proj, 2, 8, proj_b, nullptr, nullptr,
        nullptr, 0, EPI_NONE, t0, nullptr, DD,
        nullptr, nullptr, nullptr, nullptr, nullptr, nullptr);
    // LN->relu->fo1 (into fo), LN->hnbf
    k_lnchain<<<MM, blk, 0, stream>>>(t0, pln_g, pln_b, aln_g, aln_b, fo, hnbf);
    // fused k|v: (M,256)@(256,512) -> kvbf [MM][512]
    k_mgemm<<<dim3(MM/128, 4), blk, 0, stream>>>((const unsigned short*)hnbf, DD,
        (const unsigned short*)sw_kv, 4, 8, nullptr, nullptr, nullptr,
        nullptr, 0, EPI_NONE, nullptr, kvbf, D2,
        nullptr, nullptr, nullptr, nullptr, nullptr, nullptr);
    // q: token-0 rows only (lda = 9*256)
    k_mgemm<<<dim3(BB/128, 2), blk, 0, stream>>>((const unsigned short*)hnbf, NN*DD,
        (const unsigned short*)sw_wq, 2, 8, nullptr, nullptr, nullptr,
        nullptr, 0, EPI_NONE, nullptr, qbf, DD,
        nullptr, nullptr, nullptr, nullptr, nullptr, nullptr);
    // attention
    k_attn<<<BB, blk, 0, stream>>>(qbf, kvbf, vm, obbf);
    // fo2 = fo1[token0] + o@wo + wo_b
    k_mgemm<<<dim3(BB/128, 2), blk, 0, stream>>>((const unsigned short*)obbf, DD,
        (const unsigned short*)sw_wo, 2, 8, wo_b, nullptr, nullptr,
        fo, NN*DD, EPI_RES, fo2, nullptr, DD,
        nullptr, nullptr, nullptr, nullptr, nullptr, nullptr);
    // hn2 = ln(fo2)
    k_ln<<<BB, blk, 0, stream>>>(fo2, fln_g, fln_b, hn2bf);
    // g1 = gelu(hn2@ff_w1 + b1)
    k_mgemm<<<dim3(BB/128, 4), blk, 0, stream>>>((const unsigned short*)hn2bf, DD,
        (const unsigned short*)sw_ff1, 4, 8, ff_b1, nullptr, nullptr,
        nullptr, 0, EPI_GELU, nullptr, g1bf, D2,
        nullptr, nullptr, nullptr, nullptr, nullptr, nullptr);
    // feat = fo2 + g1@ff_w2 + b2
    k_mgemm<<<dim3(BB/128, 2), blk, 0, stream>>>((const unsigned short*)g1bf, D2,
        (const unsigned short*)sw_ff2, 2, 16, ff_b2, nullptr, nullptr,
        fo2, DD, EPI_RES, nullptr, featbf, DD,
        nullptr, nullptr, nullptr, nullptr, nullptr, nullptr);
    // pred head -> out (fp32)
    k_pred2<<<dim3(BB/128, (TT+7)/8), blk, 0, stream>>>((const unsigned short*)featbf,
        (const unsigned short*)sw_pred, pb1, pbg, pbb, pw2, out);
}

// Round 6
// 780.643 us; speedup vs baseline: 1.2944x; 1.2944x over previous
//
#include <hip/hip_runtime.h>
#include <hip/hip_bf16.h>
#include <math.h>

typedef __hip_bfloat16 bf16;
typedef __attribute__((ext_vector_type(8))) short short8;
typedef __attribute__((ext_vector_type(4))) float f32x4;

#define BB 4096
#define LL 8
#define NN 9
#define SS 877
#define DD 256
#define D2 512
#define TT 137
#define HH 128
#define MM (BB*NN)   // 36864
#define KP1 896      // 877 padded to mult of 32

__device__ __forceinline__ float lrelu(float x){ return x > 0.f ? x : 0.01f*x; }
__device__ __forceinline__ float gelu_tanh(float x){
    float x3 = x*x*x;
    float t = tanhf(0.7978845608028654f*(x + 0.044715f*x3));
    return 0.5f*x*(1.f + t);
}
__device__ __forceinline__ short f2b(float x){
    union { bf16 h; short s; } u; u.h = __float2bfloat16(x); return u.s;
}
__device__ __forceinline__ float b2f(bf16 v){ return __bfloat162float(v); }

// ---------- fused swizzle of ALL weights into fragment order -------------------
// dst flat = (((kb*NBt + nbOff+nbl)*8 + h)*64 + lane)*8 + j
//   k = kb*32 + (lane>>4)*8 + j ; n_local = nbl*128 + h*16 + (lane&15)
struct SwzD { const float* src; unsigned short* dst; int K; int Nloc; int NBloc;
              int NBt; int nbOff; long long base; };
struct SwzTab { SwzD d[10]; long long total; };

__global__ __launch_bounds__(256) void k_swzall(SwzTab tab){
    for (long long f0 = (long long)blockIdx.x*256 + threadIdx.x; f0 < tab.total;
         f0 += (long long)gridDim.x*256){
        int di = 0;
        #pragma unroll
        for (int q = 1; q < 10; q++) if (f0 >= tab.d[q].base) di = q;
        const SwzD dd = tab.d[di];
        long long f = f0 - dd.base;
        int j = (int)(f & 7); int lane = (int)((f>>3)&63); int h = (int)((f>>9)&7);
        long long u = f>>12;
        int nbl = (int)(u % dd.NBloc), kb = (int)(u / dd.NBloc);
        int k = kb*32 + ((lane>>4)<<3) + j;
        int n = nbl*128 + h*16 + (lane&15);
        float v = (k < dd.K) ? dd.src[(size_t)k*dd.Nloc + n] : 0.f;
        size_t dsti = ((((size_t)kb*dd.NBt + dd.nbOff + nbl)*8 + h)*64 + lane)*8 + j;
        dd.dst[dsti] = (unsigned short)f2b(v);
    }
}

// ---------- prep: valid mask + x -> bf16 [MM][896] (zero-padded) ---------------
__global__ __launch_bounds__(256) void k_prep(const float* __restrict__ src,
                                              const float* __restrict__ srcn,
                                              float* __restrict__ vm,
                                              unsigned short* __restrict__ xbf){
    int m = blockIdx.x; int b = m / NN, n = m % NN;
    const float* row = (n == 0) ? src + (size_t)b*SS
                                : srcn + ((size_t)b*LL + (n-1))*SS;
    unsigned short* orow = xbf + (size_t)m*KP1;
    float s = 0.f;
    for (int i = threadIdx.x; i < KP1; i += 256){
        float v = (i < SS) ? row[i] : 0.f;
        s += fabsf(v);
        orow[i] = (unsigned short)f2b(v);
    }
    #pragma unroll
    for (int o = 32; o > 0; o >>= 1) s += __shfl_xor(s, o);
    __shared__ float part[4];
    if ((threadIdx.x & 63) == 0) part[threadIdx.x>>6] = s;
    __syncthreads();
    if (threadIdx.x == 0)
        vm[m] = ((part[0]+part[1]+part[2]+part[3]) > 0.f) ? 1.f : 0.f;
}

// ---------- epilogue modes ------------------------------------------------------
#define EPI_NONE 0
#define EPI_BN_LEAKY 1
#define EPI_RES 2
#define EPI_GELU 3

// ---------- MFMA GEMM: 1 barrier/K-step, A dist-2 reg prefetch + LDS dbuf ------
__global__ __launch_bounds__(256) void k_mgemm(
    const unsigned short* __restrict__ A, int lda,
    const unsigned short* __restrict__ Wsw, int NBt, int nKb,
    const float* __restrict__ bias, const float* __restrict__ bng,
    const float* __restrict__ bnb, const float* __restrict__ res,
    int res_stride, int mode,
    float* __restrict__ out, bf16* __restrict__ outbf, int ldo)
{
    __shared__ short8 As[2][8][64];     // [buf][row-grp][lane] 16KB
    int row0 = blockIdx.x*128;
    int nb = blockIdx.y;
    int tid = threadIdx.x;
    int wv = tid>>6, lane = tid&63;
    int wr = wv>>1, wc = wv&1, quad = lane>>4, l15 = lane&15;

    f32x4 zz = {0.f,0.f,0.f,0.f};
    f32x4 acc[4][4];
    #pragma unroll
    for (int i=0;i<4;i++){ acc[i][0]=zz; acc[i][1]=zz; acc[i][2]=zz; acc[i][3]=zz; }

    int m0 = tid>>2, k8 = tid&3;
    int dst0 = (m0>>4)*64 + (m0&15) + (k8<<4);   // uint4 units
    int dst1 = dst0 + 256;                       // row m0+64
    const uint4* A0p = (const uint4*)(A + (size_t)(row0+m0)*lda + k8*8);
    const uint4* A1p = (const uint4*)(A + (size_t)(row0+m0+64)*lda + k8*8);
    int ldau4 = lda >> 3;                        // uint4 per row... (unused, stride via kb*4)
    (void)ldau4;
    const short8* W8 = (const short8*)Wsw;

    uint4 a1r0, a1r1, a2r0, a2r1;
    short8 w[4], nw[4];

    // prologue: A(0) -> LDS[0]; A(1) -> regs; W(0) -> regs
    {
        uint4 x0 = A0p[0], x1 = A1p[0];
        ((uint4*)As[0])[dst0] = x0;
        ((uint4*)As[0])[dst1] = x1;
        a1r0 = A0p[4]; a1r1 = A1p[4];
        #pragma unroll
        for (int h = 0; h < 4; h++)
            w[h] = W8[((size_t)nb*8 + wc*4 + h)*64 + lane];
    }
    for (int kb = 0; kb < nKb; kb++){
        int buf = kb & 1;
        if (kb+2 < nKb){ a2r0 = A0p[(kb+2)*4]; a2r1 = A1p[(kb+2)*4]; }
        if (kb+1 < nKb){
            #pragma unroll
            for (int h = 0; h < 4; h++)
                nw[h] = W8[((size_t)((kb+1)*NBt + nb)*8 + wc*4 + h)*64 + lane];
        }
        __syncthreads();                 // As[buf] ready (written prev iter)
        short8 afr[4];
        #pragma unroll
        for (int i = 0; i < 4; i++) afr[i] = As[buf][wr*4+i][lane];
        #pragma unroll
        for (int i = 0; i < 4; i++)
            #pragma unroll
            for (int h = 0; h < 4; h++)
                acc[i][h] = __builtin_amdgcn_mfma_f32_16x16x32_bf16(afr[i], w[h], acc[i][h], 0,0,0);
        if (kb+1 < nKb){
            ((uint4*)As[buf^1])[dst0] = a1r0;
            ((uint4*)As[buf^1])[dst1] = a1r1;
            a1r0 = a2r0; a1r1 = a2r1;
            #pragma unroll
            for (int h = 0; h < 4; h++) w[h] = nw[h];
        }
    }

    const float inv = rsqrtf(1.f + 1e-5f);
    #pragma unroll
    for (int i = 0; i < 4; i++){
        int rbase = row0 + wr*64 + i*16 + quad*4;
        #pragma unroll
        for (int h = 0; h < 4; h++){
            int c = nb*128 + wc*64 + h*16 + l15;
            float bi = bias ? bias[c] : 0.f;
            #pragma unroll
            for (int reg = 0; reg < 4; reg++){
                int r = rbase + reg;
                float y = acc[i][h][reg] + bi;
                if (mode == EPI_BN_LEAKY)      y = lrelu(y*(bng[c]*inv) + bnb[c]);
                else if (mode == EPI_RES)      y += res[(size_t)r*res_stride + c];
                else if (mode == EPI_GELU)     y = gelu_tanh(y);
                if (out)   out[(size_t)r*ldo + c] = y;
                if (outbf) outbf[(size_t)r*ldo + c] = __float2bfloat16(y);
            }
        }
    }
}

// ---------- pred head: per (row-block, t), same 1-barrier pipeline -------------
__global__ __launch_bounds__(256) void k_pred(
    const unsigned short* __restrict__ feat,   // bf16 [4096][256]
    const unsigned short* __restrict__ Wsw,    // [(t*8+kb)][h][lane][j]
    const float* __restrict__ b1, const float* __restrict__ bg,
    const float* __restrict__ bb, const float* __restrict__ w2,
    float* __restrict__ outp)
{
    __shared__ short8 As[2][8][64];
    int row0 = blockIdx.x*128;
    int t = blockIdx.y;
    int tid = threadIdx.x;
    int wv = tid>>6, lane = tid&63;
    int quad = lane>>4, l15 = lane&15;

    const float inv = rsqrtf(1.f + 1e-5f);
    float b1v[8], bgv[8], bbv[8], w2v[8];
    #pragma unroll
    for (int h = 0; h < 8; h++){
        int hc = t*HH + h*16 + l15;
        b1v[h] = b1[hc]; bgv[h] = bg[hc]*inv; bbv[h] = bb[hc]; w2v[h] = w2[hc];
    }

    f32x4 zz = {0.f,0.f,0.f,0.f};
    f32x4 acc[2][8];
    #pragma unroll
    for (int i=0;i<2;i++)
        #pragma unroll
        for (int h=0;h<8;h++) acc[i][h] = zz;

    int m0 = tid>>2, k8 = tid&3;
    int dst0 = (m0>>4)*64 + (m0&15) + (k8<<4);
    int dst1 = dst0 + 256;
    const uint4* A0p = (const uint4*)(feat + (size_t)(row0+m0)*DD + k8*8);
    const uint4* A1p = (const uint4*)(feat + (size_t)(row0+m0+64)*DD + k8*8);
    const short8* W8 = (const short8*)Wsw;

    uint4 a1r0, a1r1, a2r0, a2r1;
    short8 w[8], nw[8];
    {
        uint4 x0 = A0p[0], x1 = A1p[0];
        ((uint4*)As[0])[dst0] = x0;
        ((uint4*)As[0])[dst1] = x1;
        a1r0 = A0p[4]; a1r1 = A1p[4];
        #pragma unroll
        for (int h = 0; h < 8; h++)
            w[h] = W8[((size_t)(t*8)*8 + h)*64 + lane];
    }
    for (int kb = 0; kb < 8; kb++){
        int buf = kb & 1;
        if (kb+2 < 8){ a2r0 = A0p[(kb+2)*4]; a2r1 = A1p[(kb+2)*4]; }
        if (kb+1 < 8){
            #pragma unroll
            for (int h = 0; h < 8; h++)
                nw[h] = W8[((size_t)(t*8 + kb+1)*8 + h)*64 + lane];
        }
        __syncthreads();
        short8 afr[2];
        #pragma unroll
        for (int i = 0; i < 2; i++) afr[i] = As[buf][wv*2+i][lane];
        #pragma unroll
        for (int i = 0; i < 2; i++)
            #pragma unroll
            for (int h = 0; h < 8; h++)
                acc[i][h] = __builtin_amdgcn_mfma_f32_16x16x32_bf16(afr[i], w[h], acc[i][h], 0,0,0);
        if (kb+1 < 8){
            ((uint4*)As[buf^1])[dst0] = a1r0;
            ((uint4*)As[buf^1])[dst1] = a1r1;
            a1r0 = a2r0; a1r1 = a2r1;
            #pragma unroll
            for (int h = 0; h < 8; h++) w[h] = nw[h];
        }
    }

    #pragma unroll
    for (int i = 0; i < 2; i++){
        #pragma unroll
        for (int reg = 0; reg < 4; reg++){
            float p = 0.f;
            #pragma unroll
            for (int h = 0; h < 8; h++){
                float y = (acc[i][h][reg] + b1v[h])*bgv[h] + bbv[h];
                p += lrelu(y) * w2v[h];
            }
            p += __shfl_xor(p, 1);
            p += __shfl_xor(p, 2);
            p += __shfl_xor(p, 4);
            p += __shfl_xor(p, 8);
            if (l15 == 0){
                int r = row0 + wv*32 + i*16 + quad*4 + reg;
                outp[(size_t)r*TT + t] = p;
            }
        }
    }
}

// ---------- role + class tokens (fp32 in-place) + bf16 copy --------------------
__global__ __launch_bounds__(256) void k_rolecls(const float* __restrict__ tokc,
                                                 const float* __restrict__ tokn1,
                                                 const float* __restrict__ tokn2,
                                                 const float* __restrict__ cell_tokens,
                                                 const float* __restrict__ cell_inf,
                                                 const float* __restrict__ vm,
                                                 float* __restrict__ fo,
                                                 bf16* __restrict__ fobf){
    int m = blockIdx.x, d = threadIdx.x;
    int n = m % NN;
    float v = vm[m];
    const float* role = (n == 0) ? tokc : (n <= 4 ? tokn1 : tokn2);
    float cl = 0.f;
    #pragma unroll
    for (int c = 0; c < 13; c++)
        cl += cell_inf[(size_t)m*13 + c] * cell_tokens[c*DD + d];
    float y = fo[(size_t)m*DD + d] + (role[d] + cl) * v;
    fo[(size_t)m*DD + d] = y;
    fobf[(size_t)m*DD + d] = __float2bfloat16(y);
}

// ---------- LN helpers (wave shfl + 2 barriers) --------------------------------
__device__ __forceinline__ float blksum(float v, float* part){
    #pragma unroll
    for (int o = 32; o > 0; o >>= 1) v += __shfl_xor(v, o);
    __syncthreads();
    if ((threadIdx.x & 63) == 0) part[threadIdx.x>>6] = v;
    __syncthreads();
    return part[0]+part[1]+part[2]+part[3];
}

__global__ __launch_bounds__(256) void k_lnchain(const float* __restrict__ in,
                                                 const float* __restrict__ g1, const float* __restrict__ b1,
                                                 const float* __restrict__ g2, const float* __restrict__ b2,
                                                 float* __restrict__ fo1, bf16* __restrict__ hn){
    __shared__ float part[4];
    int m = blockIdx.x, d = threadIdx.x;
    float x = in[(size_t)m*DD + d];
    float mu = blksum(x, part) * (1.f/256.f);
    float dx = x - mu;
    float var = blksum(dx*dx, part) * (1.f/256.f);
    float y = dx * rsqrtf(var + 1e-5f) * g1[d] + b1[d];
    y = fmaxf(y, 0.f);
    fo1[(size_t)m*DD + d] = y;
    float mu2 = blksum(y, part) * (1.f/256.f);
    float dy = y - mu2;
    float var2 = blksum(dy*dy, part) * (1.f/256.f);
    hn[(size_t)m*DD + d] = __float2bfloat16(dy * rsqrtf(var2 + 1e-5f) * g2[d] + b2[d]);
}

__global__ __launch_bounds__(256) void k_ln(const float* __restrict__ in,
                                            const float* __restrict__ g, const float* __restrict__ b,
                                            bf16* __restrict__ out){
    __shared__ float part[4];
    int m = blockIdx.x, d = threadIdx.x;
    float x = in[(size_t)m*DD + d];
    float mu = blksum(x, part) * (1.f/256.f);
    float dx = x - mu;
    float var = blksum(dx*dx, part) * (1.f/256.f);
    out[(size_t)m*DD + d] = __float2bfloat16(dx * rsqrtf(var + 1e-5f) * g[d] + b[d]);
}

// ---------- attention (query token 0 only), combined kv [MM][512] --------------
__global__ __launch_bounds__(256) void k_attn(const bf16* __restrict__ q,
                                              const bf16* __restrict__ kv,
                                              const float* __restrict__ vm,
                                              bf16* __restrict__ o){
    int b = blockIdx.x, t = threadIdx.x;
    __shared__ float ks[NN][DD];
    __shared__ float vs[NN][DD];
    __shared__ float qs[DD];
    __shared__ float sc[4][NN];
    __shared__ float val[NN];
    qs[t] = b2f(q[(size_t)b*DD + t]);
    for (int j = 0; j < NN; j++){
        ks[j][t] = b2f(kv[((size_t)b*NN + j)*D2 + t]);
        vs[j][t] = b2f(kv[((size_t)b*NN + j)*D2 + DD + t]);
    }
    if (t < NN) val[t] = vm[b*NN + t];
    __syncthreads();
    if (t < 4*NN){
        int h = t / NN, j = t % NN;
        float s = 0.f;
        for (int d = 0; d < 64; d++) s += qs[h*64+d] * ks[j][h*64+d];
        s *= 0.125f;
        if (!(val[j] > 0.f)) s = -1e9f;
        sc[h][j] = s;
    }
    __syncthreads();
    if (t < 4){
        float mx = -1e30f;
        for (int j = 0; j < NN; j++) mx = fmaxf(mx, sc[t][j]);
        float den = 0.f;
        for (int j = 0; j < NN; j++){ float e = expf(sc[t][j]-mx); sc[t][j] = e; den += e; }
        float iv = 1.f/den;
        for (int j = 0; j < NN; j++) sc[t][j] *= iv;
    }
    __syncthreads();
    int h = t >> 6;
    float acc = 0.f;
    for (int j = 0; j < NN; j++) acc += sc[h][j] * vs[j][t];
    o[(size_t)b*DD + t] = __float2bfloat16(acc);
}

extern "C" void kernel_launch(void* const* d_in, const int* in_sizes, int n_in,
                              void* d_out, int out_size, void* d_ws, size_t ws_size,
                              hipStream_t stream) {
    const float* src      = (const float*)d_in[0];
    const float* srcn     = (const float*)d_in[1];
    const float* cell_inf = (const float*)d_in[2];
    const float* enc_w1   = (const float*)d_in[3];
    const float* enc_b1   = (const float*)d_in[4];
    const float* bn1g     = (const float*)d_in[5];
    const float* bn1b     = (const float*)d_in[6];
    const float* enc_w2   = (const float*)d_in[7];
    const float* enc_b2   = (const float*)d_in[8];
    const float* bn2g     = (const float*)d_in[9];
    const float* bn2b     = (const float*)d_in[10];
    const float* proj_w   = (const float*)d_in[11];
    const float* proj_b   = (const float*)d_in[12];
    const float* pln_g    = (const float*)d_in[13];
    const float* pln_b    = (const float*)d_in[14];
    const float* aln_g    = (const float*)d_in[15];
    const float* aln_b    = (const float*)d_in[16];
    const float* wq       = (const float*)d_in[17];
    const float* wk       = (const float*)d_in[18];
    const float* wv       = (const float*)d_in[19];
    const float* wo       = (const float*)d_in[20];
    const float* wo_b     = (const float*)d_in[21];
    const float* fln_g    = (const float*)d_in[22];
    const float* fln_b    = (const float*)d_in[23];
    const float* ff_w1    = (const float*)d_in[24];
    const float* ff_b1    = (const float*)d_in[25];
    const float* ff_w2    = (const float*)d_in[26];
    const float* ff_b2    = (const float*)d_in[27];
    const float* tokc     = (const float*)d_in[28];
    const float* tokn1    = (const float*)d_in[29];
    const float* tokn2    = (const float*)d_in[30];
    const float* cell_tok = (const float*)d_in[31];
    const float* pw1      = (const float*)d_in[32];
    const float* pb1      = (const float*)d_in[33];
    const float* pbg      = (const float*)d_in[34];
    const float* pbb      = (const float*)d_in[35];
    const float* pw2      = (const float*)d_in[36];
    float* out            = (float*)d_out;

    char* base = (char*)d_ws;
    size_t off = 0;
    auto alloc = [&](size_t bytes)->char*{
        char* p = base + off;
        off += (bytes + 255) & ~(size_t)255;
        return p;
    };
    // swizzled weights (bf16)
    bf16* sw_enc1 = (bf16*)alloc((size_t)KP1*D2*2);
    bf16* sw_enc2 = (bf16*)alloc((size_t)D2*DD*2);
    bf16* sw_proj = (bf16*)alloc((size_t)DD*DD*2);
    bf16* sw_wq   = (bf16*)alloc((size_t)DD*DD*2);
    bf16* sw_kv   = (bf16*)alloc((size_t)DD*D2*2);     // wk|wv combined, NBt=4
    bf16* sw_wo   = (bf16*)alloc((size_t)DD*DD*2);
    bf16* sw_ff1  = (bf16*)alloc((size_t)DD*D2*2);
    bf16* sw_ff2  = (bf16*)alloc((size_t)D2*DD*2);
    bf16* sw_pred = (bf16*)alloc((size_t)TT*DD*HH*2);
    // activations (with aliasing)
    float* vm    = (float*)alloc((size_t)MM*4);
    char*  xreg  = alloc((size_t)MM*KP1*2);           // xbf; later fo + fobf
    bf16*  h1bf  = (bf16*)alloc((size_t)MM*D2*2);     // later: kv combined [MM][512]
    float* t0    = (float*)alloc((size_t)MM*DD*4);
    bf16*  hnbf  = (bf16*)alloc((size_t)MM*DD*2);
    bf16*  qbf   = (bf16*)alloc((size_t)BB*DD*2);
    bf16*  obbf  = (bf16*)alloc((size_t)BB*DD*2);
    float* fo2   = (float*)alloc((size_t)BB*DD*4);
    bf16*  hn2bf = (bf16*)alloc((size_t)BB*DD*2);
    bf16*  g1bf  = (bf16*)alloc((size_t)BB*D2*2);
    bf16*  featbf= (bf16*)alloc((size_t)BB*DD*2);
    // aliases
    unsigned short* xbf = (unsigned short*)xreg;                  // dead after enc1
    float* fo   = (float*)xreg;                                   // MM*DD fp32
    bf16*  fobf = (bf16*)(xreg + (size_t)MM*DD*4);                // MM*DD bf16
    bf16* kvbf  = h1bf;                                           // after enc2

    dim3 blk(256);

    // fused weight swizzle
    SwzTab tab;
    long long cum = 0;
    auto mk = [&](int slot, const float* s, bf16* d, int K, int Kpad, int Nloc,
                  int NBt, int nbOff){
        tab.d[slot] = SwzD{ s, (unsigned short*)d, K, Nloc, Nloc/128, NBt, nbOff, cum };
        cum += (long long)Kpad*Nloc;
    };
    mk(0, enc_w1, sw_enc1, SS, KP1, D2, 4, 0);
    mk(1, enc_w2, sw_enc2, D2, D2, DD, 2, 0);
    mk(2, proj_w, sw_proj, DD, DD, DD, 2, 0);
    mk(3, wq,     sw_wq,   DD, DD, DD, 2, 0);
    mk(4, wk,     sw_kv,   DD, DD, DD, 4, 0);
    mk(5, wv,     sw_kv,   DD, DD, DD, 4, 2);
    mk(6, wo,     sw_wo,   DD, DD, DD, 2, 0);
    mk(7, ff_w1,  sw_ff1,  DD, DD, D2, 4, 0);
    mk(8, ff_w2,  sw_ff2,  D2, D2, DD, 2, 0);
    mk(9, pw1,    sw_pred, TT*DD, TT*DD, HH, 1, 0);
    tab.total = cum;
    k_swzall<<<1024, blk, 0, stream>>>(tab);

    // prep: vm + bf16 x
    k_prep<<<MM, blk, 0, stream>>>(src, srcn, vm, xbf);

    // enc1: (M,896)@(896,512) -> bn1 -> leaky -> h1bf (bf16)
    k_mgemm<<<dim3(MM/128, 4), blk, 0, stream>>>(xbf, KP1,
        (const unsigned short*)sw_enc1, 4, KP1/32, enc_b1, bn1g, bn1b,
        nullptr, 0, EPI_BN_LEAKY, nullptr, h1bf, D2);
    // enc2: (M,512)@(512,256) -> bn2 -> leaky -> fo (fp32)  [xbf now dead]
    k_mgemm<<<dim3(MM/128, 2), blk, 0, stream>>>((const unsigned short*)h1bf, D2,
        (const unsigned short*)sw_enc2, 2, 16, enc_b2, bn2g, bn2b,
        nullptr, 0, EPI_BN_LEAKY, fo, nullptr, DD);
    // + (role + class)*vm ; emit bf16 copy
    k_rolecls<<<MM, blk, 0, stream>>>(tokc, tokn1, tokn2, cell_tok, cell_inf, vm, fo, fobf);
    // proj -> t0 (fp32)
    k_mgemm<<<dim3(MM/128, 2), blk, 0, stream>>>((const unsigned short*)fobf, DD,
        (const unsigned short*)sw_proj, 2, 8, proj_b, nullptr, nullptr,
        nullptr, 0, EPI_NONE, t0, nullptr, DD);
    // LN->relu->fo1 (into fo), LN->hnbf
    k_lnchain<<<MM, blk, 0, stream>>>(t0, pln_g, pln_b, aln_g, aln_b, fo, hnbf);
    // fused k|v: (M,256)@(256,512) -> kvbf [MM][512]
    k_mgemm<<<dim3(MM/128, 4), blk, 0, stream>>>((const unsigned short*)hnbf, DD,
        (const unsigned short*)sw_kv, 4, 8, nullptr, nullptr, nullptr,
        nullptr, 0, EPI_NONE, nullptr, kvbf, D2);
    // q: token-0 rows only (lda = 9*256)
    k_mgemm<<<dim3(BB/128, 2), blk, 0, stream>>>((const unsigned short*)hnbf, NN*DD,
        (const unsigned short*)sw_wq, 2, 8, nullptr, nullptr, nullptr,
        nullptr, 0, EPI_NONE, nullptr, qbf, DD);
    // attention
    k_attn<<<BB, blk, 0, stream>>>(qbf, kvbf, vm, obbf);
    // fo2 = fo1[token0] + o@wo + wo_b
    k_mgemm<<<dim3(BB/128, 2), blk, 0, stream>>>((const unsigned short*)obbf, DD,
        (const unsigned short*)sw_wo, 2, 8, wo_b, nullptr, nullptr,
        fo, NN*DD, EPI_RES, fo2, nullptr, DD);
    // hn2 = ln(fo2)
    k_ln<<<BB, blk, 0, stream>>>(fo2, fln_g, fln_b, hn2bf);
    // g1 = gelu(hn2@ff_w1 + b1)
    k_mgemm<<<dim3(BB/128, 4), blk, 0, stream>>>((const unsigned short*)hn2bf, DD,
        (const unsigned short*)sw_ff1, 4, 8, ff_b1, nullptr, nullptr,
        nullptr, 0, EPI_GELU, nullptr, g1bf, D2);
    // feat = fo2 + g1@ff_w2 + b2
    k_mgemm<<<dim3(BB/128, 2), blk, 0, stream>>>((const unsigned short*)g1bf, D2,
        (const unsigned short*)sw_ff2, 2, 16, ff_b2, nullptr, nullptr,
        fo2, DD, EPI_RES, nullptr, featbf, DD);
    // pred head -> out (fp32)
    k_pred<<<dim3(BB/128, TT), blk, 0, stream>>>((const unsigned short*)featbf,
        (const unsigned short*)sw_pred, pb1, pbg, pbb, pw2, out);
}

// Round 7
// 757.113 us; speedup vs baseline: 1.3346x; 1.0311x over previous
//
#include <hip/hip_runtime.h>
#include <hip/hip_bf16.h>
#include <math.h>

typedef __hip_bfloat16 bf16;
typedef __attribute__((ext_vector_type(8))) short short8;
typedef __attribute__((ext_vector_type(4))) float f32x4;

#define BB 4096
#define LL 8
#define NN 9
#define SS 877
#define DD 256
#define D2 512
#define TT 137
#define HH 128
#define MM (BB*NN)   // 36864
#define KP1 896      // 877 padded to mult of 32

__device__ __forceinline__ float lrelu(float x){ return x > 0.f ? x : 0.01f*x; }
__device__ __forceinline__ float gelu_tanh(float x){
    float x3 = x*x*x;
    float t = tanhf(0.7978845608028654f*(x + 0.044715f*x3));
    return 0.5f*x*(1.f + t);
}
__device__ __forceinline__ short f2b(float x){
    union { bf16 h; short s; } u; u.h = __float2bfloat16(x); return u.s;
}
__device__ __forceinline__ float b2f(bf16 v){ return __bfloat162float(v); }

// ---------- fused swizzle of ALL weights into fragment order -------------------
// dst flat = (((kb*NBt + nbOff+nbl)*8 + h)*64 + lane)*8 + j
//   k = kb*32 + (lane>>4)*8 + j ; n_local = nbl*128 + h*16 + (lane&15)
struct SwzD { const float* src; unsigned short* dst; int K; int Nloc; int NBloc;
              int NBt; int nbOff; long long base; };
struct SwzTab { SwzD d[10]; long long total; };

__global__ __launch_bounds__(256) void k_swzall(SwzTab tab){
    for (long long f0 = (long long)blockIdx.x*256 + threadIdx.x; f0 < tab.total;
         f0 += (long long)gridDim.x*256){
        int di = 0;
        #pragma unroll
        for (int q = 1; q < 10; q++) if (f0 >= tab.d[q].base) di = q;
        const SwzD dd = tab.d[di];
        long long f = f0 - dd.base;
        int j = (int)(f & 7); int lane = (int)((f>>3)&63); int h = (int)((f>>9)&7);
        long long u = f>>12;
        int nbl = (int)(u % dd.NBloc), kb = (int)(u / dd.NBloc);
        int k = kb*32 + ((lane>>4)<<3) + j;
        int n = nbl*128 + h*16 + (lane&15);
        float v = (k < dd.K) ? dd.src[(size_t)k*dd.Nloc + n] : 0.f;
        size_t dsti = ((((size_t)kb*dd.NBt + dd.nbOff + nbl)*8 + h)*64 + lane)*8 + j;
        dd.dst[dsti] = (unsigned short)f2b(v);
    }
}

// ---------- prep: valid mask + x -> bf16 [MM][896] (zero-padded) ---------------
__global__ __launch_bounds__(256) void k_prep(const float* __restrict__ src,
                                              const float* __restrict__ srcn,
                                              float* __restrict__ vm,
                                              unsigned short* __restrict__ xbf){
    int m = blockIdx.x; int b = m / NN, n = m % NN;
    const float* row = (n == 0) ? src + (size_t)b*SS
                                : srcn + ((size_t)b*LL + (n-1))*SS;
    unsigned short* orow = xbf + (size_t)m*KP1;
    float s = 0.f;
    for (int i = threadIdx.x; i < KP1; i += 256){
        float v = (i < SS) ? row[i] : 0.f;
        s += fabsf(v);
        orow[i] = (unsigned short)f2b(v);
    }
    #pragma unroll
    for (int o = 32; o > 0; o >>= 1) s += __shfl_xor(s, o);
    __shared__ float part[4];
    if ((threadIdx.x & 63) == 0) part[threadIdx.x>>6] = s;
    __syncthreads();
    if (threadIdx.x == 0)
        vm[m] = ((part[0]+part[1]+part[2]+part[3]) > 0.f) ? 1.f : 0.f;
}

// ---------- epilogue modes ------------------------------------------------------
#define EPI_NONE 0
#define EPI_BN_LEAKY 1
#define EPI_RES 2
#define EPI_GELU 3

// ---------- MFMA GEMM: 1 barrier/K-step, XCD-affine 1-D grid -------------------
// grid = RB*NBt blocks; rb = (id%8) + 8*((id/8) % (RB/8)); nb = (id/8)/(RB/8)
__global__ __launch_bounds__(256) void k_mgemm(
    const unsigned short* __restrict__ A, int lda,
    const unsigned short* __restrict__ Wsw, int RB, int NBt, int nKb,
    const float* __restrict__ bias, const float* __restrict__ bng,
    const float* __restrict__ bnb, const float* __restrict__ res,
    int res_stride, int mode,
    float* __restrict__ out, bf16* __restrict__ outbf, int ldo)
{
    __shared__ short8 As[2][8][64];     // [buf][row-grp][lane] 16KB
    int id = blockIdx.x;
    int rbg = RB >> 3;
    int loc = id >> 3;
    int rb = (id & 7) + ((loc % rbg) << 3);
    int nb = loc / rbg;
    int row0 = rb*128;
    int tid = threadIdx.x;
    int wv = tid>>6, lane = tid&63;
    int wr = wv>>1, wc = wv&1, quad = lane>>4, l15 = lane&15;

    f32x4 zz = {0.f,0.f,0.f,0.f};
    f32x4 acc[4][4];
    #pragma unroll
    for (int i=0;i<4;i++){ acc[i][0]=zz; acc[i][1]=zz; acc[i][2]=zz; acc[i][3]=zz; }

    int m0 = tid>>2, k8 = tid&3;
    int dst0 = (m0>>4)*64 + (m0&15) + (k8<<4);   // uint4 units
    int dst1 = dst0 + 256;                       // row m0+64
    const uint4* A0p = (const uint4*)(A + (size_t)(row0+m0)*lda + k8*8);
    const uint4* A1p = (const uint4*)(A + (size_t)(row0+m0+64)*lda + k8*8);
    int ldu = lda >> 3;                          // uint4 per A row
    const short8* W8 = (const short8*)Wsw;

    uint4 a1r0, a1r1, a2r0, a2r1;
    short8 w[4], nw[4];

    // prologue: A(0) -> LDS[0]; A(1) -> regs; W(0) -> regs
    {
        uint4 x0 = A0p[0], x1 = A1p[0];
        ((uint4*)As[0])[dst0] = x0;
        ((uint4*)As[0])[dst1] = x1;
        a1r0 = A0p[4]; a1r1 = A1p[4];
        #pragma unroll
        for (int h = 0; h < 4; h++)
            w[h] = W8[((size_t)nb*8 + wc*4 + h)*64 + lane];
    }
    (void)ldu;
    for (int kb = 0; kb < nKb; kb++){
        int buf = kb & 1;
        if (kb+2 < nKb){ a2r0 = A0p[(kb+2)*4]; a2r1 = A1p[(kb+2)*4]; }
        if (kb+1 < nKb){
            #pragma unroll
            for (int h = 0; h < 4; h++)
                nw[h] = W8[((size_t)((kb+1)*NBt + nb)*8 + wc*4 + h)*64 + lane];
        }
        __syncthreads();                 // As[buf] ready (written prev iter)
        short8 afr[4];
        #pragma unroll
        for (int i = 0; i < 4; i++) afr[i] = As[buf][wr*4+i][lane];
        #pragma unroll
        for (int i = 0; i < 4; i++)
            #pragma unroll
            for (int h = 0; h < 4; h++)
                acc[i][h] = __builtin_amdgcn_mfma_f32_16x16x32_bf16(afr[i], w[h], acc[i][h], 0,0,0);
        if (kb+1 < nKb){
            ((uint4*)As[buf^1])[dst0] = a1r0;
            ((uint4*)As[buf^1])[dst1] = a1r1;
            a1r0 = a2r0; a1r1 = a2r1;
            #pragma unroll
            for (int h = 0; h < 4; h++) w[h] = nw[h];
        }
    }

    const float inv = rsqrtf(1.f + 1e-5f);
    #pragma unroll
    for (int i = 0; i < 4; i++){
        int rbase = row0 + wr*64 + i*16 + quad*4;
        #pragma unroll
        for (int h = 0; h < 4; h++){
            int c = nb*128 + wc*64 + h*16 + l15;
            float bi = bias ? bias[c] : 0.f;
            #pragma unroll
            for (int reg = 0; reg < 4; reg++){
                int r = rbase + reg;
                float y = acc[i][h][reg] + bi;
                if (mode == EPI_BN_LEAKY)      y = lrelu(y*(bng[c]*inv) + bnb[c]);
                else if (mode == EPI_RES)      y += res[(size_t)r*res_stride + c];
                else if (mode == EPI_GELU)     y = gelu_tanh(y);
                if (out)   out[(size_t)r*ldo + c] = y;
                if (outbf) outbf[(size_t)r*ldo + c] = __float2bfloat16(y);
            }
        }
    }
}

// ---------- pred head v3: no LDS, no barriers, XCD-affine t --------------------
// grid = 8*18*32 blocks; xcd = id%8; loc = id/8; tg = loc/32; x = loc%32;
// t = xcd + 8*tg (guard t<137); rows x*128..
__global__ __launch_bounds__(256) void k_pred(
    const unsigned short* __restrict__ feat,   // bf16 [4096][256]
    const unsigned short* __restrict__ Wsw,    // [(t*8+kb)][h][lane][j]
    const float* __restrict__ b1, const float* __restrict__ bg,
    const float* __restrict__ bb, const float* __restrict__ w2,
    float* __restrict__ outp)
{
    int id = blockIdx.x;
    int loc = id >> 3;
    int t = (id & 7) + ((loc >> 5) << 3);
    if (t >= TT) return;
    int row0 = (loc & 31) * 128;
    int tid = threadIdx.x;
    int wv = tid>>6, lane = tid&63;
    int quad = lane>>4, l15 = lane&15;

    f32x4 zz = {0.f,0.f,0.f,0.f};
    f32x4 acc[2][8];
    #pragma unroll
    for (int i=0;i<2;i++)
        #pragma unroll
        for (int h=0;h<8;h++) acc[i][h] = zz;

    const short8* W8 = (const short8*)Wsw;
    // A-frag rows for this wave: i=0 -> row0+wv*32+l15 ; i=1 -> +16
    const short8* Ap0 = (const short8*)(feat + (size_t)(row0 + wv*32 + l15)*DD + quad*8);
    const short8* Ap1 = (const short8*)(feat + (size_t)(row0 + wv*32 + 16 + l15)*DD + quad*8);

    #pragma unroll 2
    for (int kb = 0; kb < 8; kb++){
        short8 a0 = Ap0[kb*4];          // kb*32 elems = kb*4 short8
        short8 a1 = Ap1[kb*4];
        short8 w[8];
        #pragma unroll
        for (int h = 0; h < 8; h++)
            w[h] = W8[((size_t)(t*8 + kb)*8 + h)*64 + lane];
        #pragma unroll
        for (int h = 0; h < 8; h++){
            acc[0][h] = __builtin_amdgcn_mfma_f32_16x16x32_bf16(a0, w[h], acc[0][h], 0,0,0);
            acc[1][h] = __builtin_amdgcn_mfma_f32_16x16x32_bf16(a1, w[h], acc[1][h], 0,0,0);
        }
    }

    const float inv = rsqrtf(1.f + 1e-5f);
    float b1v[8], bgv[8], bbv[8], w2v[8];
    #pragma unroll
    for (int h = 0; h < 8; h++){
        int hc = t*HH + h*16 + l15;
        b1v[h] = b1[hc]; bgv[h] = bg[hc]*inv; bbv[h] = bb[hc]; w2v[h] = w2[hc];
    }
    #pragma unroll
    for (int i = 0; i < 2; i++){
        #pragma unroll
        for (int reg = 0; reg < 4; reg++){
            float p = 0.f;
            #pragma unroll
            for (int h = 0; h < 8; h++){
                float y = (acc[i][h][reg] + b1v[h])*bgv[h] + bbv[h];
                p += lrelu(y) * w2v[h];
            }
            p += __shfl_xor(p, 1);
            p += __shfl_xor(p, 2);
            p += __shfl_xor(p, 4);
            p += __shfl_xor(p, 8);
            if (l15 == 0){
                int r = row0 + wv*32 + i*16 + quad*4 + reg;
                outp[(size_t)r*TT + t] = p;
            }
        }
    }
}

// ---------- role + class tokens -> bf16 only -----------------------------------
__global__ __launch_bounds__(256) void k_rolecls(const float* __restrict__ tokc,
                                                 const float* __restrict__ tokn1,
                                                 const float* __restrict__ tokn2,
                                                 const float* __restrict__ cell_tokens,
                                                 const float* __restrict__ cell_inf,
                                                 const float* __restrict__ vm,
                                                 const float* __restrict__ fo,
                                                 bf16* __restrict__ fobf){
    int m = blockIdx.x, d = threadIdx.x;
    int n = m % NN;
    float v = vm[m];
    const float* role = (n == 0) ? tokc : (n <= 4 ? tokn1 : tokn2);
    float cl = 0.f;
    #pragma unroll
    for (int c = 0; c < 13; c++)
        cl += cell_inf[(size_t)m*13 + c] * cell_tokens[c*DD + d];
    float y = fo[(size_t)m*DD + d] + (role[d] + cl) * v;
    fobf[(size_t)m*DD + d] = __float2bfloat16(y);
}

// ---------- LN helpers (wave shfl + 2 barriers) --------------------------------
__device__ __forceinline__ float blksum(float v, float* part){
    #pragma unroll
    for (int o = 32; o > 0; o >>= 1) v += __shfl_xor(v, o);
    __syncthreads();
    if ((threadIdx.x & 63) == 0) part[threadIdx.x>>6] = v;
    __syncthreads();
    return part[0]+part[1]+part[2]+part[3];
}

// t0 -> LN(proj)->relu -> fo1 (fp32, ONLY token0 rows, compact BBxDD) ; LN -> hn (bf16 all)
__global__ __launch_bounds__(256) void k_lnchain(const float* __restrict__ in,
                                                 const float* __restrict__ g1, const float* __restrict__ b1,
                                                 const float* __restrict__ g2, const float* __restrict__ b2,
                                                 float* __restrict__ fo1c, bf16* __restrict__ hn){
    __shared__ float part[4];
    int m = blockIdx.x, d = threadIdx.x;
    int b = m / NN; int n = m - b*NN;
    float x = in[(size_t)m*DD + d];
    float mu = blksum(x, part) * (1.f/256.f);
    float dx = x - mu;
    float var = blksum(dx*dx, part) * (1.f/256.f);
    float y = dx * rsqrtf(var + 1e-5f) * g1[d] + b1[d];
    y = fmaxf(y, 0.f);
    if (n == 0) fo1c[(size_t)b*DD + d] = y;
    float mu2 = blksum(y, part) * (1.f/256.f);
    float dy = y - mu2;
    float var2 = blksum(dy*dy, part) * (1.f/256.f);
    hn[(size_t)m*DD + d] = __float2bfloat16(dy * rsqrtf(var2 + 1e-5f) * g2[d] + b2[d]);
}

__global__ __launch_bounds__(256) void k_ln(const float* __restrict__ in,
                                            const float* __restrict__ g, const float* __restrict__ b,
                                            bf16* __restrict__ out){
    __shared__ float part[4];
    int m = blockIdx.x, d = threadIdx.x;
    float x = in[(size_t)m*DD + d];
    float mu = blksum(x, part) * (1.f/256.f);
    float dx = x - mu;
    float var = blksum(dx*dx, part) * (1.f/256.f);
    out[(size_t)m*DD + d] = __float2bfloat16(dx * rsqrtf(var + 1e-5f) * g[d] + b[d]);
}

// ---------- attention (query token 0 only), combined kv [MM][512] --------------
__global__ __launch_bounds__(256) void k_attn(const bf16* __restrict__ q,
                                              const bf16* __restrict__ kv,
                                              const float* __restrict__ vm,
                                              bf16* __restrict__ o){
    int b = blockIdx.x, t = threadIdx.x;
    __shared__ float ks[NN][DD];
    __shared__ float vs[NN][DD];
    __shared__ float qs[DD];
    __shared__ float sc[4][NN];
    __shared__ float val[NN];
    qs[t] = b2f(q[(size_t)b*DD + t]);
    for (int j = 0; j < NN; j++){
        ks[j][t] = b2f(kv[((size_t)b*NN + j)*D2 + t]);
        vs[j][t] = b2f(kv[((size_t)b*NN + j)*D2 + DD + t]);
    }
    if (t < NN) val[t] = vm[b*NN + t];
    __syncthreads();
    if (t < 4*NN){
        int h = t / NN, j = t % NN;
        float s = 0.f;
        for (int d = 0; d < 64; d++) s += qs[h*64+d] * ks[j][h*64+d];
        s *= 0.125f;
        if (!(val[j] > 0.f)) s = -1e9f;
        sc[h][j] = s;
    }
    __syncthreads();
    if (t < 4){
        float mx = -1e30f;
        for (int j = 0; j < NN; j++) mx = fmaxf(mx, sc[t][j]);
        float den = 0.f;
        for (int j = 0; j < NN; j++){ float e = expf(sc[t][j]-mx); sc[t][j] = e; den += e; }
        float iv = 1.f/den;
        for (int j = 0; j < NN; j++) sc[t][j] *= iv;
    }
    __syncthreads();
    int h = t >> 6;
    float acc = 0.f;
    for (int j = 0; j < NN; j++) acc += sc[h][j] * vs[j][t];
    o[(size_t)b*DD + t] = __float2bfloat16(acc);
}

extern "C" void kernel_launch(void* const* d_in, const int* in_sizes, int n_in,
                              void* d_out, int out_size, void* d_ws, size_t ws_size,
                              hipStream_t stream) {
    const float* src      = (const float*)d_in[0];
    const float* srcn     = (const float*)d_in[1];
    const float* cell_inf = (const float*)d_in[2];
    const float* enc_w1   = (const float*)d_in[3];
    const float* enc_b1   = (const float*)d_in[4];
    const float* bn1g     = (const float*)d_in[5];
    const float* bn1b     = (const float*)d_in[6];
    const float* enc_w2   = (const float*)d_in[7];
    const float* enc_b2   = (const float*)d_in[8];
    const float* bn2g     = (const float*)d_in[9];
    const float* bn2b     = (const float*)d_in[10];
    const float* proj_w   = (const float*)d_in[11];
    const float* proj_b   = (const float*)d_in[12];
    const float* pln_g    = (const float*)d_in[13];
    const float* pln_b    = (const float*)d_in[14];
    const float* aln_g    = (const float*)d_in[15];
    const float* aln_b    = (const float*)d_in[16];
    const float* wq       = (const float*)d_in[17];
    const float* wk       = (const float*)d_in[18];
    const float* wv       = (const float*)d_in[19];
    const float* wo       = (const float*)d_in[20];
    const float* wo_b     = (const float*)d_in[21];
    const float* fln_g    = (const float*)d_in[22];
    const float* fln_b    = (const float*)d_in[23];
    const float* ff_w1    = (const float*)d_in[24];
    const float* ff_b1    = (const float*)d_in[25];
    const float* ff_w2    = (const float*)d_in[26];
    const float* ff_b2    = (const float*)d_in[27];
    const float* tokc     = (const float*)d_in[28];
    const float* tokn1    = (const float*)d_in[29];
    const float* tokn2    = (const float*)d_in[30];
    const float* cell_tok = (const float*)d_in[31];
    const float* pw1      = (const float*)d_in[32];
    const float* pb1      = (const float*)d_in[33];
    const float* pbg      = (const float*)d_in[34];
    const float* pbb      = (const float*)d_in[35];
    const float* pw2      = (const float*)d_in[36];
    float* out            = (float*)d_out;

    char* base = (char*)d_ws;
    size_t off = 0;
    auto alloc = [&](size_t bytes)->char*{
        char* p = base + off;
        off += (bytes + 255) & ~(size_t)255;
        return p;
    };
    // swizzled weights (bf16)
    bf16* sw_enc1 = (bf16*)alloc((size_t)KP1*D2*2);
    bf16* sw_enc2 = (bf16*)alloc((size_t)D2*DD*2);
    bf16* sw_proj = (bf16*)alloc((size_t)DD*DD*2);
    bf16* sw_wq   = (bf16*)alloc((size_t)DD*DD*2);
    bf16* sw_kv   = (bf16*)alloc((size_t)DD*D2*2);     // wk|wv combined, NBt=4
    bf16* sw_wo   = (bf16*)alloc((size_t)DD*DD*2);
    bf16* sw_ff1  = (bf16*)alloc((size_t)DD*D2*2);
    bf16* sw_ff2  = (bf16*)alloc((size_t)D2*DD*2);
    bf16* sw_pred = (bf16*)alloc((size_t)TT*DD*HH*2);
    // activations (with aliasing)
    float* vm    = (float*)alloc((size_t)MM*4);
    char*  xreg  = alloc((size_t)MM*KP1*2);           // xbf; later fo + fobf
    bf16*  h1bf  = (bf16*)alloc((size_t)MM*D2*2);     // later: kv combined [MM][512]
    float* t0    = (float*)alloc((size_t)MM*DD*4);
    bf16*  hnbf  = (bf16*)alloc((size_t)MM*DD*2);
    float* fo1c  = (float*)alloc((size_t)BB*DD*4);    // token0 rows of fo1 (fp32)
    bf16*  qbf   = (bf16*)alloc((size_t)BB*DD*2);
    bf16*  obbf  = (bf16*)alloc((size_t)BB*DD*2);
    float* fo2   = (float*)alloc((size_t)BB*DD*4);
    bf16*  hn2bf = (bf16*)alloc((size_t)BB*DD*2);
    bf16*  g1bf  = (bf16*)alloc((size_t)BB*D2*2);
    bf16*  featbf= (bf16*)alloc((size_t)BB*DD*2);
    // aliases
    unsigned short* xbf = (unsigned short*)xreg;                  // dead after enc1
    float* fo   = (float*)xreg;                                   // MM*DD fp32
    bf16*  fobf = (bf16*)(xreg + (size_t)MM*DD*4);                // MM*DD bf16
    bf16* kvbf  = h1bf;                                           // after enc2

    dim3 blk(256);

    // fused weight swizzle
    SwzTab tab;
    long long cum = 0;
    auto mk = [&](int slot, const float* s, bf16* d, int K, int Kpad, int Nloc,
                  int NBt, int nbOff){
        tab.d[slot] = SwzD{ s, (unsigned short*)d, K, Nloc, Nloc/128, NBt, nbOff, cum };
        cum += (long long)Kpad*Nloc;
    };
    mk(0, enc_w1, sw_enc1, SS, KP1, D2, 4, 0);
    mk(1, enc_w2, sw_enc2, D2, D2, DD, 2, 0);
    mk(2, proj_w, sw_proj, DD, DD, DD, 2, 0);
    mk(3, wq,     sw_wq,   DD, DD, DD, 2, 0);
    mk(4, wk,     sw_kv,   DD, DD, DD, 4, 0);
    mk(5, wv,     sw_kv,   DD, DD, DD, 4, 2);
    mk(6, wo,     sw_wo,   DD, DD, DD, 2, 0);
    mk(7, ff_w1,  sw_ff1,  DD, DD, D2, 4, 0);
    mk(8, ff_w2,  sw_ff2,  D2, D2, DD, 2, 0);
    mk(9, pw1,    sw_pred, TT*DD, TT*DD, HH, 1, 0);
    tab.total = cum;
    k_swzall<<<1024, blk, 0, stream>>>(tab);

    // prep: vm + bf16 x
    k_prep<<<MM, blk, 0, stream>>>(src, srcn, vm, xbf);

    // enc1: (M,896)@(896,512) -> bn1 -> leaky -> h1bf (bf16)
    k_mgemm<<<dim3((MM/128)*4), blk, 0, stream>>>(xbf, KP1,
        (const unsigned short*)sw_enc1, MM/128, 4, KP1/32, enc_b1, bn1g, bn1b,
        nullptr, 0, EPI_BN_LEAKY, nullptr, h1bf, D2);
    // enc2: (M,512)@(512,256) -> bn2 -> leaky -> fo (fp32)  [xbf now dead]
    k_mgemm<<<dim3((MM/128)*2), blk, 0, stream>>>((const unsigned short*)h1bf, D2,
        (const unsigned short*)sw_enc2, MM/128, 2, 16, enc_b2, bn2g, bn2b,
        nullptr, 0, EPI_BN_LEAKY, fo, nullptr, DD);
    // + (role + class)*vm -> bf16 only
    k_rolecls<<<MM, blk, 0, stream>>>(tokc, tokn1, tokn2, cell_tok, cell_inf, vm, fo, fobf);
    // proj -> t0 (fp32)
    k_mgemm<<<dim3((MM/128)*2), blk, 0, stream>>>((const unsigned short*)fobf, DD,
        (const unsigned short*)sw_proj, MM/128, 2, 8, proj_b, nullptr, nullptr,
        nullptr, 0, EPI_NONE, t0, nullptr, DD);
    // LN->relu->fo1c (token0 fp32), LN->hnbf
    k_lnchain<<<MM, blk, 0, stream>>>(t0, pln_g, pln_b, aln_g, aln_b, fo1c, hnbf);
    // fused k|v: (M,256)@(256,512) -> kvbf [MM][512]
    k_mgemm<<<dim3((MM/128)*4), blk, 0, stream>>>((const unsigned short*)hnbf, DD,
        (const unsigned short*)sw_kv, MM/128, 4, 8, nullptr, nullptr, nullptr,
        nullptr, 0, EPI_NONE, nullptr, kvbf, D2);
    // q: token-0 rows only (lda = 9*256)
    k_mgemm<<<dim3((BB/128)*2), blk, 0, stream>>>((const unsigned short*)hnbf, NN*DD,
        (const unsigned short*)sw_wq, BB/128, 2, 8, nullptr, nullptr, nullptr,
        nullptr, 0, EPI_NONE, nullptr, qbf, DD);
    // attention
    k_attn<<<BB, blk, 0, stream>>>(qbf, kvbf, vm, obbf);
    // fo2 = fo1c + o@wo + wo_b
    k_mgemm<<<dim3((BB/128)*2), blk, 0, stream>>>((const unsigned short*)obbf, DD,
        (const unsigned short*)sw_wo, BB/128, 2, 8, wo_b, nullptr, nullptr,
        fo1c, DD, EPI_RES, fo2, nullptr, DD);
    // hn2 = ln(fo2)
    k_ln<<<BB, blk, 0, stream>>>(fo2, fln_g, fln_b, hn2bf);
    // g1 = gelu(hn2@ff_w1 + b1)
    k_mgemm<<<dim3((BB/128)*4), blk, 0, stream>>>((const unsigned short*)hn2bf, DD,
        (const unsigned short*)sw_ff1, BB/128, 4, 8, ff_b1, nullptr, nullptr,
        nullptr, 0, EPI_GELU, nullptr, g1bf, D2);
    // feat = fo2 + g1@ff_w2 + b2
    k_mgemm<<<dim3((BB/128)*2), blk, 0, stream>>>((const unsigned short*)g1bf, D2,
        (const unsigned short*)sw_ff2, BB/128, 2, 16, ff_b2, nullptr, nullptr,
        fo2, DD, EPI_RES, nullptr, featbf, DD);
    // pred head -> out (fp32)
    k_pred<<<dim3(8*18*32), blk, 0, stream>>>((const unsigned short*)featbf,
        (const unsigned short*)sw_pred, pb1, pbg, pbb, pw2, out);
}